// Round 7
// baseline (209.542 us; speedup 1.0000x reference)
//
#include <hip/hip_runtime.h>

#define NCACHE 384

__device__ __forceinline__ unsigned int sortable_bits(float f) {
    unsigned int u = __float_as_uint(f);
    return (u & 0x80000000u) ? ~u : (u | 0x80000000u);
}

// One group: broadcast-read 8 keys (uniform addr), then 4 cmp/addc per key.
// All per-iteration state lives inside the asm block -> no compiler glue.
#define RANK_GROUP(g) do {                                                    \
    unsigned long long t0,t1,t2,t3,t4,t5,t6,t7;                               \
    asm volatile(                                                             \
        "ds_read_b64 %[t0], %[ad] offset:%c[o0]\n\t"                          \
        "ds_read_b64 %[t1], %[ad] offset:%c[o1]\n\t"                          \
        "ds_read_b64 %[t2], %[ad] offset:%c[o2]\n\t"                          \
        "ds_read_b64 %[t3], %[ad] offset:%c[o3]\n\t"                          \
        "ds_read_b64 %[t4], %[ad] offset:%c[o4]\n\t"                          \
        "ds_read_b64 %[t5], %[ad] offset:%c[o5]\n\t"                          \
        "ds_read_b64 %[t6], %[ad] offset:%c[o6]\n\t"                          \
        "ds_read_b64 %[t7], %[ad] offset:%c[o7]\n\t"                          \
        "s_waitcnt lgkmcnt(0)\n\t"                                            \
        "v_cmp_lt_u64 vcc, %[t0], %[k0]\n\t"                                  \
        "v_addc_co_u32 %[r0], vcc, 0, %[r0], vcc\n\t"                         \
        "v_cmp_lt_u64 vcc, %[t0], %[k1]\n\t"                                  \
        "v_addc_co_u32 %[r1], vcc, 0, %[r1], vcc\n\t"                         \
        "v_cmp_lt_u64 vcc, %[t1], %[k0]\n\t"                                  \
        "v_addc_co_u32 %[r0], vcc, 0, %[r0], vcc\n\t"                         \
        "v_cmp_lt_u64 vcc, %[t1], %[k1]\n\t"                                  \
        "v_addc_co_u32 %[r1], vcc, 0, %[r1], vcc\n\t"                         \
        "v_cmp_lt_u64 vcc, %[t2], %[k0]\n\t"                                  \
        "v_addc_co_u32 %[r0], vcc, 0, %[r0], vcc\n\t"                         \
        "v_cmp_lt_u64 vcc, %[t2], %[k1]\n\t"                                  \
        "v_addc_co_u32 %[r1], vcc, 0, %[r1], vcc\n\t"                         \
        "v_cmp_lt_u64 vcc, %[t3], %[k0]\n\t"                                  \
        "v_addc_co_u32 %[r0], vcc, 0, %[r0], vcc\n\t"                         \
        "v_cmp_lt_u64 vcc, %[t3], %[k1]\n\t"                                  \
        "v_addc_co_u32 %[r1], vcc, 0, %[r1], vcc\n\t"                         \
        "v_cmp_lt_u64 vcc, %[t4], %[k0]\n\t"                                  \
        "v_addc_co_u32 %[r0], vcc, 0, %[r0], vcc\n\t"                         \
        "v_cmp_lt_u64 vcc, %[t4], %[k1]\n\t"                                  \
        "v_addc_co_u32 %[r1], vcc, 0, %[r1], vcc\n\t"                         \
        "v_cmp_lt_u64 vcc, %[t5], %[k0]\n\t"                                  \
        "v_addc_co_u32 %[r0], vcc, 0, %[r0], vcc\n\t"                         \
        "v_cmp_lt_u64 vcc, %[t5], %[k1]\n\t"                                  \
        "v_addc_co_u32 %[r1], vcc, 0, %[r1], vcc\n\t"                         \
        "v_cmp_lt_u64 vcc, %[t6], %[k0]\n\t"                                  \
        "v_addc_co_u32 %[r0], vcc, 0, %[r0], vcc\n\t"                         \
        "v_cmp_lt_u64 vcc, %[t6], %[k1]\n\t"                                  \
        "v_addc_co_u32 %[r1], vcc, 0, %[r1], vcc\n\t"                         \
        "v_cmp_lt_u64 vcc, %[t7], %[k0]\n\t"                                  \
        "v_addc_co_u32 %[r0], vcc, 0, %[r0], vcc\n\t"                         \
        "v_cmp_lt_u64 vcc, %[t7], %[k1]\n\t"                                  \
        "v_addc_co_u32 %[r1], vcc, 0, %[r1], vcc"                             \
        : [r0]"+v"(r0), [r1]"+v"(r1),                                         \
          [t0]"=&v"(t0), [t1]"=&v"(t1), [t2]"=&v"(t2), [t3]"=&v"(t3),         \
          [t4]"=&v"(t4), [t5]"=&v"(t5), [t6]"=&v"(t6), [t7]"=&v"(t7)          \
        : [ad]"v"(kaddr), [k0]"v"(k0), [k1]"v"(k1),                           \
          [o0]"i"(64*(g)+ 0), [o1]"i"(64*(g)+ 8), [o2]"i"(64*(g)+16),         \
          [o3]"i"(64*(g)+24), [o4]"i"(64*(g)+32), [o5]"i"(64*(g)+40),         \
          [o6]"i"(64*(g)+48), [o7]"i"(64*(g)+56)                              \
        : "vcc", "memory");                                                   \
} while (0)

// 256 threads = 4 waves; wave w handles b = blockIdx.x*4 + w entirely.
__global__ __launch_bounds__(256) void fused_kernel(
    const float*  __restrict__ cache,        // (384,5)
    const float*  __restrict__ refdirs,      // (B,3)
    const float*  __restrict__ normal,       // (B,3)
    const float4* __restrict__ samp_rays4,   // B*96 float4
    const float4* __restrict__ samp_mip4,    // B*32 float4
    float* __restrict__ out, int B)
{
#pragma clang fp contract(off)
    __shared__ float sdx[NCACHE], sdy[NCACHE], sdz[NCACHE], smip[NCACHE];
    __shared__ __align__(16) unsigned long long keys[4][NCACHE];
    __shared__ unsigned int bitmap[4][12];

    const int tid  = threadIdx.x;
    const int wave = tid >> 6;
    const int lane = tid & 63;
    const int b    = blockIdx.x * 4 + wave;

    // Early-issue pass-through copy loads (hide HBM under the rank loop).
    const int b0 = blockIdx.x * 4;
    const int i0 = tid, i1 = tid + 256;
    const int bb0 = b0 + (i0 >> 7), off0 = i0 & 127;
    const int bb1 = b0 + (i1 >> 7), off1 = i1 & 127;
    const float4 c0 = (off0 < 96) ? samp_rays4[(size_t)bb0 * 96 + off0]
                                  : samp_mip4[(size_t)bb0 * 32 + (off0 - 96)];
    const float4 c1 = (off1 < 96) ? samp_rays4[(size_t)bb1 * 96 + off1]
                                  : samp_mip4[(size_t)bb1 * 32 + (off1 - 96)];

    // Stage cache into LDS (cooperative, once per block)
    for (int m = tid; m < NCACHE; m += 256) {
        sdx[m]  = cache[m * 5 + 0];
        sdy[m]  = cache[m * 5 + 1];
        sdz[m]  = cache[m * 5 + 2];
        smip[m] = cache[m * 5 + 3];
    }
    if (tid < 48) (&bitmap[0][0])[tid] = 0u;

    const float nx = normal[b * 3 + 0], ny = normal[b * 3 + 1], nz = normal[b * 3 + 2];
    const float rx = refdirs[b * 3 + 0], ry = refdirs[b * 3 + 1], rz = refdirs[b * 3 + 2];

    __syncthreads();

    // Scores -> stable keys (FMA left-chains, bit-exact vs reference; -0.0 -> +0.0).
    // Keep the two m<128 keys of this lane in registers; write all 384 to LDS.
    unsigned long long k0 = 0, k1 = 0;
#pragma unroll
    for (int c = 0; c < 6; ++c) {
        const int m = c * 64 + lane;
        float dx = sdx[m], dy = sdy[m], dz = sdz[m];
        float hemi = __builtin_fmaf(nz, dz, __builtin_fmaf(ny, dy, nx * dx));
        float sim  = __builtin_fmaf(rz, dz, __builtin_fmaf(ry, dy, rx * dx));
        float val  = (hemi > 0.0f) ? -sim : 0.0f;
        val = val + 0.0f;
        unsigned long long key =
            ((unsigned long long)sortable_bits(val) << 32) | (unsigned int)m;
        keys[wave][m] = key;
        if (c == 0) k0 = key;
        if (c == 1) k1 = key;
    }
    __syncthreads();

    // Transposed rank loop: broadcast key_j (uniform ds_read, conflict-free),
    // each lane accumulates its two ranks with cmp+addc. 4 VALU serve 128 pairs.
    const unsigned int kaddr = (unsigned int)(size_t)&keys[wave][0];
    unsigned int r0 = 0, r1 = 0;
    RANK_GROUP(0);  RANK_GROUP(1);  RANK_GROUP(2);  RANK_GROUP(3);
    RANK_GROUP(4);  RANK_GROUP(5);  RANK_GROUP(6);  RANK_GROUP(7);
    RANK_GROUP(8);  RANK_GROUP(9);  RANK_GROUP(10); RANK_GROUP(11);
    RANK_GROUP(12); RANK_GROUP(13); RANK_GROUP(14); RANK_GROUP(15);
    RANK_GROUP(16); RANK_GROUP(17); RANK_GROUP(18); RANK_GROUP(19);
    RANK_GROUP(20); RANK_GROUP(21); RANK_GROUP(22); RANK_GROUP(23);
    RANK_GROUP(24); RANK_GROUP(25); RANK_GROUP(26); RANK_GROUP(27);
    RANK_GROUP(28); RANK_GROUP(29); RANK_GROUP(30); RANK_GROUP(31);
    RANK_GROUP(32); RANK_GROUP(33); RANK_GROUP(34); RANK_GROUP(35);
    RANK_GROUP(36); RANK_GROUP(37); RANK_GROUP(38); RANK_GROUP(39);
    RANK_GROUP(40); RANK_GROUP(41); RANK_GROUP(42); RANK_GROUP(43);
    RANK_GROUP(44); RANK_GROUP(45); RANK_GROUP(46); RANK_GROUP(47);

    // Ranks are distinct in [0,384). Output slot = #{selected ranks < r}.
    atomicOr(&bitmap[wave][r0 >> 5], 1u << (r0 & 31));
    atomicOr(&bitmap[wave][r1 >> 5], 1u << (r1 & 31));
    __syncthreads();

    float* out_rays = out;
    float* out_mip  = out + (size_t)B * 768;

    {
        const int wi = (int)r0 >> 5;
        int s = __popc(bitmap[wave][wi] & ((1u << (r0 & 31)) - 1u));
        for (int w = 0; w < wi; ++w) s += __popc(bitmap[wave][w]);
        const size_t rb = (size_t)b * 768 + 384 + (size_t)s * 3;
        out_rays[rb + 0] = sdx[r0];
        out_rays[rb + 1] = sdy[r0];
        out_rays[rb + 2] = sdz[r0];
        out_mip[(size_t)b * 256 + 128 + s] = smip[r0];
    }
    {
        const int wi = (int)r1 >> 5;
        int s = __popc(bitmap[wave][wi] & ((1u << (r1 & 31)) - 1u));
        for (int w = 0; w < wi; ++w) s += __popc(bitmap[wave][w]);
        const size_t rb = (size_t)b * 768 + 384 + (size_t)s * 3;
        out_rays[rb + 0] = sdx[r1];
        out_rays[rb + 1] = sdy[r1];
        out_rays[rb + 2] = sdz[r1];
        out_mip[(size_t)b * 256 + 128 + s] = smip[r1];
    }

    // Pass-through copy stores (loads issued at kernel entry).
    float4* out4     = (float4*)out;
    float4* out_mip4 = (float4*)(out + (size_t)B * 768);
    if (off0 < 96) out4[(size_t)bb0 * 192 + off0] = c0;
    else           out_mip4[(size_t)bb0 * 64 + (off0 - 96)] = c0;
    if (off1 < 96) out4[(size_t)bb1 * 192 + off1] = c1;
    else           out_mip4[(size_t)bb1 * 64 + (off1 - 96)] = c1;
}

extern "C" void kernel_launch(void* const* d_in, const int* in_sizes, int n_in,
                              void* d_out, int out_size, void* d_ws, size_t ws_size,
                              hipStream_t stream) {
    const float* cache       = (const float*)d_in[0];
    const float* refdirs     = (const float*)d_in[1];
    const float* normal      = (const float*)d_in[2];
    const float* samp_rays   = (const float*)d_in[3];
    const float* samp_mipval = (const float*)d_in[4];
    float* out = (float*)d_out;

    const int B = in_sizes[1] / 3;  // 65536

    fused_kernel<<<B / 4, 256, 0, stream>>>(cache, refdirs, normal,
                                            (const float4*)samp_rays,
                                            (const float4*)samp_mipval,
                                            out, B);
}